// Round 1
// baseline (768.170 us; speedup 1.0000x reference)
//
#include <hip/hip_runtime.h>

#define D 64  // feature dim == units == 64 for this problem

// ---------------------------------------------------------------------------
// Kernel 1: edge scatter-aggregate.  agg[dst[e]] += w[e] * emb[src[e]]
// 16 threads per edge, each handling 4 consecutive floats (one float4 gather,
// four scalar fp32 atomics).  Atomics are device-scope by default (G12).
// ---------------------------------------------------------------------------
__global__ __launch_bounds__(256) void scatter_edges(
    const float* __restrict__ emb,
    const int*   __restrict__ src,
    const int*   __restrict__ dst,
    const float* __restrict__ w,
    float*       __restrict__ agg,
    int E)
{
    int tid  = blockIdx.x * 256 + threadIdx.x;
    int e    = tid >> 4;          // edge index
    if (e >= E) return;
    int part = tid & 15;          // which float4 of the 16 in a 64-float row

    int   s  = src[e];
    int   d  = dst[e];
    float ww = w[e];

    float4 v = reinterpret_cast<const float4*>(emb + (size_t)s * D)[part];

    float* o = agg + (size_t)d * D + part * 4;
    atomicAdd(o + 0, v.x * ww);
    atomicAdd(o + 1, v.y * ww);
    atomicAdd(o + 2, v.z * ww);
    atomicAdd(o + 3, v.w * ww);
}

// ---------------------------------------------------------------------------
// Kernel 2: out = relu(agg @ W),  agg: [N,64], W: [64,64], out: [N,64]
// Lane j holds column j of W in 64 VGPRs (coalesced load, L2-cached).
// Each block processes a 64-row tile of agg staged in LDS; A-values are read
// with wave-uniform addresses -> LDS broadcast (conflict-free), float4-wide,
// so the k-loop is 16 ds_read_b128 + 64 v_fmac_f32 per row per wave.
// ---------------------------------------------------------------------------
__global__ __launch_bounds__(256) void gemm_relu(
    const float* __restrict__ agg,
    const float* __restrict__ W,
    float*       __restrict__ out,
    int N)
{
    const int lane = threadIdx.x & 63;
    const int wave = threadIdx.x >> 6;

    // W column j (= lane) into registers: W[k][j] for k = 0..63
    float wcol[D];
#pragma unroll
    for (int k = 0; k < D; ++k) wcol[k] = W[k * D + lane];

    __shared__ float At[64 * D];  // 16 KiB tile of agg rows

    const int row0 = blockIdx.x * 64;

    // Cooperative tile load: 4096 floats = 1024 float4, 256 threads x 4
    for (int i = threadIdx.x; i < 1024; i += 256) {
        int r  = i >> 4;          // row within tile (16 float4 per row)
        int gr = row0 + r;
        float4 v;
        if (gr < N) v = reinterpret_cast<const float4*>(agg)[(size_t)gr * 16 + (i & 15)];
        else        v = float4{0.f, 0.f, 0.f, 0.f};
        reinterpret_cast<float4*>(At)[i] = v;
    }
    __syncthreads();

    // Each wave owns 16 consecutive rows of the tile
    for (int rr = 0; rr < 16; ++rr) {
        int r  = wave * 16 + rr;
        int gr = row0 + r;
        if (gr >= N) break;

        const float4* arow = reinterpret_cast<const float4*>(At + r * D);
        float acc = 0.f;
#pragma unroll
        for (int k4 = 0; k4 < 16; ++k4) {
            float4 a = arow[k4];               // wave-uniform -> LDS broadcast
            acc = fmaf(a.x, wcol[4 * k4 + 0], acc);
            acc = fmaf(a.y, wcol[4 * k4 + 1], acc);
            acc = fmaf(a.z, wcol[4 * k4 + 2], acc);
            acc = fmaf(a.w, wcol[4 * k4 + 3], acc);
        }
        out[(size_t)gr * D + lane] = fmaxf(acc, 0.f);
    }
}

// ---------------------------------------------------------------------------
extern "C" void kernel_launch(void* const* d_in, const int* in_sizes, int n_in,
                              void* d_out, int out_size, void* d_ws, size_t ws_size,
                              hipStream_t stream)
{
    const float* emb  = (const float*)d_in[0];  // [N, 64]
    const int*   esrc = (const int*)  d_in[1];  // [E]
    const int*   edst = (const int*)  d_in[2];  // [E]
    const float* ew   = (const float*)d_in[3];  // [E]
    const float* W    = (const float*)d_in[4];  // [64, 64]
    float*       out  = (float*)d_out;          // [N, 64]

    const int N = in_sizes[0] / D;
    const int E = in_sizes[1];

    float* agg = (float*)d_ws;                  // [N, 64] scratch, 12.8 MB

    // d_ws is poisoned 0xAA before every launch — zero the accumulator.
    hipMemsetAsync(agg, 0, (size_t)N * D * sizeof(float), stream);

    const int sgrid = (E * 16 + 255) / 256;
    scatter_edges<<<sgrid, 256, 0, stream>>>(emb, esrc, edst, ew, agg, E);

    const int tiles = (N + 63) / 64;
    gemm_relu<<<tiles, 256, 0, stream>>>(agg, W, out, N);
}

// Round 2
// 233.488 us; speedup vs baseline: 3.2900x; 3.2900x over previous
//
#include <hip/hip_runtime.h>

#define D 64  // feature dim == units == 64

// ---------------------------------------------------------------------------
// Kernel A: Z = emb @ W   (no relu here — relu is applied after aggregation)
// Lane j holds W column j in 64 VGPRs; 64-row tiles of emb staged in LDS,
// read wave-uniform (LDS broadcast, conflict-free).
// ---------------------------------------------------------------------------
__global__ __launch_bounds__(256) void gemm_z(
    const float* __restrict__ emb,
    const float* __restrict__ W,
    float*       __restrict__ Z,
    int N)
{
    const int lane = threadIdx.x & 63;
    const int wave = threadIdx.x >> 6;

    float wcol[D];
#pragma unroll
    for (int k = 0; k < D; ++k) wcol[k] = W[k * D + lane];

    __shared__ float At[64 * D];
    const int row0 = blockIdx.x * 64;

    for (int i = threadIdx.x; i < 1024; i += 256) {
        int r  = i >> 4;
        int gr = row0 + r;
        float4 v;
        if (gr < N) v = reinterpret_cast<const float4*>(emb)[(size_t)gr * 16 + (i & 15)];
        else        v = float4{0.f, 0.f, 0.f, 0.f};
        reinterpret_cast<float4*>(At)[i] = v;
    }
    __syncthreads();

    for (int rr = 0; rr < 16; ++rr) {
        int r  = wave * 16 + rr;
        int gr = row0 + r;
        if (gr >= N) break;
        const float4* arow = reinterpret_cast<const float4*>(At + r * D);
        float acc = 0.f;
#pragma unroll
        for (int k4 = 0; k4 < 16; ++k4) {
            float4 a = arow[k4];
            acc = fmaf(a.x, wcol[4 * k4 + 0], acc);
            acc = fmaf(a.y, wcol[4 * k4 + 1], acc);
            acc = fmaf(a.z, wcol[4 * k4 + 2], acc);
            acc = fmaf(a.w, wcol[4 * k4 + 3], acc);
        }
        Z[(size_t)gr * D + lane] = acc;
    }
}

// ---------------------------------------------------------------------------
// CSR construction: degree count -> exclusive scan -> bucket fill
// ---------------------------------------------------------------------------
__global__ __launch_bounds__(256) void count_deg(
    const int* __restrict__ dst, int* __restrict__ counts, int E)
{
    int e = blockIdx.x * 256 + threadIdx.x;
    if (e < E) atomicAdd(&counts[dst[e]], 1);
}

// Block-level exclusive scan: each block scans 1024 elements (256 thr x 4).
__global__ __launch_bounds__(256) void scan_blocks(
    const int* __restrict__ counts, int* __restrict__ offsets,
    int* __restrict__ partials, int N)
{
    __shared__ int sh[256];
    const int t    = threadIdx.x;
    const int base = blockIdx.x * 1024 + t * 4;

    int v0 = (base + 0 < N) ? counts[base + 0] : 0;
    int v1 = (base + 1 < N) ? counts[base + 1] : 0;
    int v2 = (base + 2 < N) ? counts[base + 2] : 0;
    int v3 = (base + 3 < N) ? counts[base + 3] : 0;

    int s0 = v0, s1 = s0 + v1, s2 = s1 + v2, s3 = s2 + v3;  // inclusive in-thread
    sh[t] = s3;
    __syncthreads();
    for (int off = 1; off < 256; off <<= 1) {
        int x = (t >= off) ? sh[t - off] : 0;
        __syncthreads();
        sh[t] += x;
        __syncthreads();
    }
    int excl = sh[t] - s3;  // exclusive prefix of this thread within block

    if (base + 0 < N) offsets[base + 0] = excl;
    if (base + 1 < N) offsets[base + 1] = excl + s0;
    if (base + 2 < N) offsets[base + 2] = excl + s1;
    if (base + 3 < N) offsets[base + 3] = excl + s2;
    if (t == 255) partials[blockIdx.x] = sh[255];
}

// Single-wave exclusive scan of <=64 block partials.
__global__ __launch_bounds__(64) void scan_partials(int* __restrict__ partials, int nb)
{
    int l    = threadIdx.x;
    int orig = (l < nb) ? partials[l] : 0;
    int v    = orig;
    for (int off = 1; off < 64; off <<= 1) {
        int x = __shfl_up(v, off, 64);
        if (l >= off) v += x;
    }
    if (l < nb) partials[l] = v - orig;  // exclusive
}

__global__ __launch_bounds__(256) void add_offsets(
    int* __restrict__ offsets, const int* __restrict__ partials,
    int* __restrict__ cursor, int N, int E)
{
    int i = blockIdx.x * 256 + threadIdx.x;
    if (i < N) {
        int o = offsets[i] + partials[i >> 10];
        offsets[i] = o;
        cursor[i]  = o;
    }
    if (i == 0) offsets[N] = E;
}

__global__ __launch_bounds__(256) void fill_csr(
    const int*   __restrict__ src,
    const int*   __restrict__ dst,
    const float* __restrict__ w,
    int*  __restrict__ cursor,
    int2* __restrict__ csr,
    int E)
{
    int e = blockIdx.x * 256 + threadIdx.x;
    if (e >= E) return;
    int pos = atomicAdd(&cursor[dst[e]], 1);
    csr[pos] = make_int2(src[e], __float_as_int(w[e]));
}

// ---------------------------------------------------------------------------
// Gather: one 64-lane wave per node.  out[i] = relu(sum_e w_e * Z[src_e])
// CSR entries are read cooperatively (lane l reads entry l) then broadcast
// via shfl; Z-row reads are fully coalesced 256 B per edge.
// ---------------------------------------------------------------------------
__global__ __launch_bounds__(256) void gather_nodes(
    const float* __restrict__ Z,
    const int*   __restrict__ offsets,
    const int2*  __restrict__ csr,
    float*       __restrict__ out,
    int N)
{
    const int node = blockIdx.x * 4 + (threadIdx.x >> 6);
    const int lane = threadIdx.x & 63;
    if (node >= N) return;

    const int beg = offsets[node];
    const int end = offsets[node + 1];

    float acc = 0.f;
    for (int c = beg; c < end; c += 64) {
        const int m = min(64, end - c);
        int2 ent = (lane < m) ? csr[c + lane] : make_int2(0, 0);
        for (int j = 0; j < m; ++j) {
            int   s = __shfl(ent.x, j, 64);
            float w = __int_as_float(__shfl(ent.y, j, 64));
            acc = fmaf(w, Z[(size_t)s * D + lane], acc);
        }
    }
    out[(size_t)node * D + lane] = fmaxf(acc, 0.f);
}

// ---------------------------------------------------------------------------
extern "C" void kernel_launch(void* const* d_in, const int* in_sizes, int n_in,
                              void* d_out, int out_size, void* d_ws, size_t ws_size,
                              hipStream_t stream)
{
    const float* emb  = (const float*)d_in[0];  // [N, 64]
    const int*   esrc = (const int*)  d_in[1];  // [E]
    const int*   edst = (const int*)  d_in[2];  // [E]
    const float* ew   = (const float*)d_in[3];  // [E]
    const float* W    = (const float*)d_in[4];  // [64, 64]
    float*       out  = (float*)d_out;          // [N, 64]

    const int N = in_sizes[0] / D;
    const int E = in_sizes[1];

    // Workspace layout (≈19.8 MB total)
    float* Z        = (float*)d_ws;             // N*64 floats
    int*   counts   = (int*)(Z + (size_t)N * D);// N
    int*   offsets  = counts + N;               // N+2 (padded for int2 alignment)
    int*   cursor   = offsets + N + 2;          // N
    int*   partials = cursor + N;               // 64
    int2*  csr      = (int2*)(partials + 64);   // E entries {src, w}

    hipMemsetAsync(counts, 0, (size_t)N * sizeof(int), stream);

    gemm_z<<<(N + 63) / 64, 256, 0, stream>>>(emb, W, Z, N);

    count_deg<<<(E + 255) / 256, 256, 0, stream>>>(edst, counts, E);

    const int nb = (N + 1023) / 1024;  // 49 <= 64
    scan_blocks<<<nb, 256, 0, stream>>>(counts, offsets, partials, N);
    scan_partials<<<1, 64, 0, stream>>>(partials, nb);
    add_offsets<<<(N + 255) / 256, 256, 0, stream>>>(offsets, partials, cursor, N, E);

    fill_csr<<<(E + 255) / 256, 256, 0, stream>>>(esrc, edst, ew, cursor, csr, E);

    gather_nodes<<<(N + 3) / 4, 256, 0, stream>>>(Z, offsets, csr, out, N);
}

// Round 3
// 199.444 us; speedup vs baseline: 3.8516x; 1.1707x over previous
//
#include <hip/hip_runtime.h>

#define D 64  // feature dim == units == 64

// ---------------------------------------------------------------------------
// Fused kernel: blocks [0, gemmTiles) compute Z = emb @ W (no relu yet);
// blocks [gemmTiles, ...) count destination degrees.  The two are independent
// and overlap: GEMM is memory-bound, degree count is atomic-latency-bound.
// ---------------------------------------------------------------------------
__global__ __launch_bounds__(256) void gemm_count(
    const float* __restrict__ emb,
    const float* __restrict__ W,
    float*       __restrict__ Z,
    const int*   __restrict__ dst,
    int*         __restrict__ counts,
    int N, int E, int gemmTiles)
{
    if ((int)blockIdx.x >= gemmTiles) {
        int e = ((int)blockIdx.x - gemmTiles) * 256 + threadIdx.x;
        if (e < E) atomicAdd(&counts[dst[e]], 1);
        return;
    }

    const int lane = threadIdx.x & 63;
    const int wave = threadIdx.x >> 6;

    float wcol[D];
#pragma unroll
    for (int k = 0; k < D; ++k) wcol[k] = W[k * D + lane];

    __shared__ float At[64 * D];
    const int row0 = blockIdx.x * 64;

    for (int i = threadIdx.x; i < 1024; i += 256) {
        int r  = i >> 4;
        int gr = row0 + r;
        float4 v;
        if (gr < N) v = reinterpret_cast<const float4*>(emb)[(size_t)gr * 16 + (i & 15)];
        else        v = float4{0.f, 0.f, 0.f, 0.f};
        reinterpret_cast<float4*>(At)[i] = v;
    }
    __syncthreads();

    for (int rr = 0; rr < 16; ++rr) {
        int r  = wave * 16 + rr;
        int gr = row0 + r;
        if (gr >= N) break;
        const float4* arow = reinterpret_cast<const float4*>(At + r * D);
        float acc = 0.f;
#pragma unroll
        for (int k4 = 0; k4 < 16; ++k4) {
            float4 a = arow[k4];
            acc = fmaf(a.x, wcol[4 * k4 + 0], acc);
            acc = fmaf(a.y, wcol[4 * k4 + 1], acc);
            acc = fmaf(a.z, wcol[4 * k4 + 2], acc);
            acc = fmaf(a.w, wcol[4 * k4 + 3], acc);
        }
        Z[(size_t)gr * D + lane] = acc;
    }
}

// Block-level exclusive scan: each block scans 1024 elements (256 thr x 4).
__global__ __launch_bounds__(256) void scan_blocks(
    const int* __restrict__ counts, int* __restrict__ offsets,
    int* __restrict__ partials, int N)
{
    __shared__ int sh[256];
    const int t    = threadIdx.x;
    const int base = blockIdx.x * 1024 + t * 4;

    int v0 = (base + 0 < N) ? counts[base + 0] : 0;
    int v1 = (base + 1 < N) ? counts[base + 1] : 0;
    int v2 = (base + 2 < N) ? counts[base + 2] : 0;
    int v3 = (base + 3 < N) ? counts[base + 3] : 0;

    int s0 = v0, s1 = s0 + v1, s2 = s1 + v2, s3 = s2 + v3;
    sh[t] = s3;
    __syncthreads();
    for (int off = 1; off < 256; off <<= 1) {
        int x = (t >= off) ? sh[t - off] : 0;
        __syncthreads();
        sh[t] += x;
        __syncthreads();
    }
    int excl = sh[t] - s3;

    if (base + 0 < N) offsets[base + 0] = excl;
    if (base + 1 < N) offsets[base + 1] = excl + s0;
    if (base + 2 < N) offsets[base + 2] = excl + s1;
    if (base + 3 < N) offsets[base + 3] = excl + s2;
    if (t == 255) partials[blockIdx.x] = sh[255];
}

// Fused: every block redundantly wave-scans the <=64 block partials (trivial),
// then applies them.  Replaces scan_partials + add_offsets (one fewer dispatch).
__global__ __launch_bounds__(256) void add_offsets(
    int* __restrict__ offsets, const int* __restrict__ partials,
    int* __restrict__ cursor, int N, int E, int nb)
{
    __shared__ int sp[64];
    if (threadIdx.x < 64) {
        int l    = threadIdx.x;
        int orig = (l < nb) ? partials[l] : 0;
        int v    = orig;
        for (int off = 1; off < 64; off <<= 1) {
            int x = __shfl_up(v, off, 64);
            if (l >= off) v += x;
        }
        sp[l] = v - orig;  // exclusive
    }
    __syncthreads();

    int i = blockIdx.x * 256 + threadIdx.x;
    if (i < N) {
        int o = offsets[i] + sp[i >> 10];
        offsets[i] = o;
        cursor[i]  = o;
    }
    if (i == 0) offsets[N] = E;
}

__global__ __launch_bounds__(256) void fill_csr(
    const int*   __restrict__ src,
    const int*   __restrict__ dst,
    const float* __restrict__ w,
    int*  __restrict__ cursor,
    int2* __restrict__ csr,
    int E)
{
    int e = blockIdx.x * 256 + threadIdx.x;
    if (e >= E) return;
    int pos = atomicAdd(&cursor[dst[e]], 1);
    csr[pos] = make_int2(src[e], __float_as_int(w[e]));
}

// ---------------------------------------------------------------------------
// Gather: one wave per node, 4 edges in flight per wave.
// Lane = (slot, q): slot = lane>>4 picks one of 4 concurrent edges,
// q = lane&15 picks the float4 within the 64-float row.  Each edge load is a
// coalesced 256 B (16 lanes x float4).  Slot partials reduced via shfl_down,
// then 16 lanes store one float4 each (coalesced 256 B row write).
// ---------------------------------------------------------------------------
__global__ __launch_bounds__(256) void gather_nodes(
    const float* __restrict__ Z,
    const int*   __restrict__ offsets,
    const int2*  __restrict__ csr,
    float*       __restrict__ out,
    int N)
{
    const int node = blockIdx.x * 4 + (threadIdx.x >> 6);
    const int lane = threadIdx.x & 63;
    if (node >= N) return;

    const int slot = lane >> 4;   // 0..3 — which edge this lane helps with
    const int q    = lane & 15;   // float4 index within the 64-float row

    const int beg = offsets[node];
    const int end = offsets[node + 1];

    const float4* Z4 = reinterpret_cast<const float4*>(Z);
    float4 acc = {0.f, 0.f, 0.f, 0.f};

    for (int c = beg; c < end; c += 64) {
        const int m = min(64, end - c);
        int2 ent = (lane < m) ? csr[c + lane] : make_int2(0, 0);
        const int tmax = (m + 3) >> 2;
        for (int t = 0; t < tmax; ++t) {
            int  j     = slot + 4 * t;
            bool valid = j < m;
            int  js    = valid ? j : 0;
            int   s  = __shfl(ent.x, js, 64);
            float wv = __int_as_float(__shfl(ent.y, js, 64));
            float w  = valid ? wv : 0.f;
            float4 z = Z4[(size_t)s * 16 + q];
            acc.x = fmaf(w, z.x, acc.x);
            acc.y = fmaf(w, z.y, acc.y);
            acc.z = fmaf(w, z.z, acc.z);
            acc.w = fmaf(w, z.w, acc.w);
        }
    }

    // Reduce the 4 slots: lane l (<16) accumulates l+32, then l+16.
#pragma unroll
    for (int off = 32; off >= 16; off >>= 1) {
        acc.x += __shfl_down(acc.x, off, 64);
        acc.y += __shfl_down(acc.y, off, 64);
        acc.z += __shfl_down(acc.z, off, 64);
        acc.w += __shfl_down(acc.w, off, 64);
    }

    if (lane < 16) {
        float4 r;
        r.x = fmaxf(acc.x, 0.f);
        r.y = fmaxf(acc.y, 0.f);
        r.z = fmaxf(acc.z, 0.f);
        r.w = fmaxf(acc.w, 0.f);
        reinterpret_cast<float4*>(out)[(size_t)node * 16 + lane] = r;
    }
}

// ---------------------------------------------------------------------------
extern "C" void kernel_launch(void* const* d_in, const int* in_sizes, int n_in,
                              void* d_out, int out_size, void* d_ws, size_t ws_size,
                              hipStream_t stream)
{
    const float* emb  = (const float*)d_in[0];  // [N, 64]
    const int*   esrc = (const int*)  d_in[1];  // [E]
    const int*   edst = (const int*)  d_in[2];  // [E]
    const float* ew   = (const float*)d_in[3];  // [E]
    const float* W    = (const float*)d_in[4];  // [64, 64]
    float*       out  = (float*)d_out;          // [N, 64]

    const int N = in_sizes[0] / D;
    const int E = in_sizes[1];

    // Workspace layout (~19.8 MB)
    float* Z        = (float*)d_ws;              // N*64 floats
    int*   counts   = (int*)(Z + (size_t)N * D); // N
    int*   offsets  = counts + N;                // N+2 (pad keeps int2 aligned)
    int*   cursor   = offsets + N + 2;           // N
    int*   partials = cursor + N;                // 64
    int2*  csr      = (int2*)(partials + 64);    // E entries {src, w-bits}

    hipMemsetAsync(counts, 0, (size_t)N * sizeof(int), stream);

    const int gemmTiles   = (N + 63) / 64;
    const int countBlocks = (E + 255) / 256;
    gemm_count<<<gemmTiles + countBlocks, 256, 0, stream>>>(
        emb, W, Z, edst, counts, N, E, gemmTiles);

    const int nb = (N + 1023) / 1024;  // 49 <= 64
    scan_blocks<<<nb, 256, 0, stream>>>(counts, offsets, partials, N);
    add_offsets<<<(N + 255) / 256, 256, 0, stream>>>(offsets, partials, cursor, N, E, nb);

    fill_csr<<<(E + 255) / 256, 256, 0, stream>>>(esrc, edst, ew, cursor, csr, E);

    gather_nodes<<<(N + 3) / 4, 256, 0, stream>>>(Z, offsets, csr, out, N);
}

// Round 4
// 182.309 us; speedup vs baseline: 4.2136x; 1.0940x over previous
//
#include <hip/hip_runtime.h>

#define D 64  // feature dim == units == 64

// ---------------------------------------------------------------------------
// Fused kernel: blocks [0, gemmTiles) compute Z = emb @ W; remaining blocks
// count destination degrees AND record each edge's rank within its bucket
// (rank[e] = atomicAdd return).  Rank store is coalesced.  The two halves are
// independent and overlap (GEMM memory-bound, count atomic-latency-bound).
// ---------------------------------------------------------------------------
__global__ __launch_bounds__(256) void gemm_count(
    const float* __restrict__ emb,
    const float* __restrict__ W,
    float*       __restrict__ Z,
    const int*   __restrict__ dst,
    int*         __restrict__ counts,
    int*         __restrict__ rank,
    int N, int E, int gemmTiles)
{
    if ((int)blockIdx.x >= gemmTiles) {
        int e = ((int)blockIdx.x - gemmTiles) * 256 + threadIdx.x;
        if (e < E) rank[e] = atomicAdd(&counts[dst[e]], 1);
        return;
    }

    const int lane = threadIdx.x & 63;
    const int wave = threadIdx.x >> 6;

    float wcol[D];
#pragma unroll
    for (int k = 0; k < D; ++k) wcol[k] = W[k * D + lane];

    __shared__ float At[64 * D];
    const int row0 = blockIdx.x * 64;

    for (int i = threadIdx.x; i < 1024; i += 256) {
        int r  = i >> 4;
        int gr = row0 + r;
        float4 v;
        if (gr < N) v = reinterpret_cast<const float4*>(emb)[(size_t)gr * 16 + (i & 15)];
        else        v = float4{0.f, 0.f, 0.f, 0.f};
        reinterpret_cast<float4*>(At)[i] = v;
    }
    __syncthreads();

    for (int rr = 0; rr < 16; ++rr) {
        int r  = wave * 16 + rr;
        int gr = row0 + r;
        if (gr >= N) break;
        const float4* arow = reinterpret_cast<const float4*>(At + r * D);
        float acc = 0.f;
#pragma unroll
        for (int k4 = 0; k4 < 16; ++k4) {
            float4 a = arow[k4];
            acc = fmaf(a.x, wcol[4 * k4 + 0], acc);
            acc = fmaf(a.y, wcol[4 * k4 + 1], acc);
            acc = fmaf(a.z, wcol[4 * k4 + 2], acc);
            acc = fmaf(a.w, wcol[4 * k4 + 3], acc);
        }
        Z[(size_t)gr * D + lane] = acc;
    }
}

// Block-level exclusive scan: each block scans 1024 elements (256 thr x 4).
// Produces per-1024-chunk-local offsets + per-chunk totals (partials).
// The <=64-entry partials scan is applied inline by downstream kernels.
__global__ __launch_bounds__(256) void scan_blocks(
    const int* __restrict__ counts, int* __restrict__ offsets,
    int* __restrict__ partials, int N)
{
    __shared__ int sh[256];
    const int t    = threadIdx.x;
    const int base = blockIdx.x * 1024 + t * 4;

    int v0 = (base + 0 < N) ? counts[base + 0] : 0;
    int v1 = (base + 1 < N) ? counts[base + 1] : 0;
    int v2 = (base + 2 < N) ? counts[base + 2] : 0;
    int v3 = (base + 3 < N) ? counts[base + 3] : 0;

    int s0 = v0, s1 = s0 + v1, s2 = s1 + v2, s3 = s2 + v3;
    sh[t] = s3;
    __syncthreads();
    for (int off = 1; off < 256; off <<= 1) {
        int x = (t >= off) ? sh[t - off] : 0;
        __syncthreads();
        sh[t] += x;
        __syncthreads();
    }
    int excl = sh[t] - s3;

    if (base + 0 < N) offsets[base + 0] = excl;
    if (base + 1 < N) offsets[base + 1] = excl + s0;
    if (base + 2 < N) offsets[base + 2] = excl + s1;
    if (base + 3 < N) offsets[base + 3] = excl + s2;
    if (t == 255) partials[blockIdx.x] = sh[255];
}

// Helper: first wave scans the <=64 chunk partials into LDS (exclusive).
__device__ __forceinline__ void scan_partials_lds(
    const int* __restrict__ partials, int nb, int* sp)
{
    if (threadIdx.x < 64) {
        int l    = threadIdx.x;
        int orig = (l < nb) ? partials[l] : 0;
        int v    = orig;
        for (int off = 1; off < 64; off <<= 1) {
            int x = __shfl_up(v, off, 64);
            if (l >= off) v += x;
        }
        sp[l] = v - orig;  // exclusive
    }
    __syncthreads();
}

// Fill: NO atomics.  eids[offset(dst)+rank] = edge id (4 B scattered store,
// fire-and-forget).  4 edges per thread via int4 loads for ILP.
__global__ __launch_bounds__(256) void fill_csr(
    const int* __restrict__ dst,
    const int* __restrict__ rank,
    const int* __restrict__ offsets,
    const int* __restrict__ partials,
    int*       __restrict__ eids,
    int E, int nb)
{
    __shared__ int sp[64];
    scan_partials_lds(partials, nb, sp);

    const int E4 = E >> 2;
    int i = blockIdx.x * 256 + threadIdx.x;
    if (i < E4) {
        int4 d4 = reinterpret_cast<const int4*>(dst)[i];
        int4 r4 = reinterpret_cast<const int4*>(rank)[i];
        int  e0 = i * 4;
        eids[offsets[d4.x] + sp[d4.x >> 10] + r4.x] = e0 + 0;
        eids[offsets[d4.y] + sp[d4.y >> 10] + r4.y] = e0 + 1;
        eids[offsets[d4.z] + sp[d4.z >> 10] + r4.z] = e0 + 2;
        eids[offsets[d4.w] + sp[d4.w >> 10] + r4.w] = e0 + 3;
    }
    // tail (E not multiple of 4)
    if (blockIdx.x == 0 && threadIdx.x == 0) {
        for (int e = E & ~3; e < E; ++e)
            eids[offsets[dst[e]] + sp[dst[e] >> 10] + rank[e]] = e;
    }
}

// ---------------------------------------------------------------------------
// Gather: one wave per node, 4 edges in flight per wave.
// lane = (slot, q): slot = lane>>4 picks one of 4 concurrent edges, q = lane&15
// the float4 within the row.  Edge src/w read indirectly via eid (L2-resident).
// ---------------------------------------------------------------------------
__global__ __launch_bounds__(256) void gather_nodes(
    const float* __restrict__ Z,
    const int*   __restrict__ offsets,
    const int*   __restrict__ partials,
    const int*   __restrict__ eids,
    const int*   __restrict__ esrc,
    const float* __restrict__ ew,
    float*       __restrict__ out,
    int N, int E, int nb)
{
    __shared__ int sp[64];
    scan_partials_lds(partials, nb, sp);

    const int node = blockIdx.x * 4 + (threadIdx.x >> 6);
    const int lane = threadIdx.x & 63;
    if (node >= N) return;

    const int slot = lane >> 4;
    const int q    = lane & 15;

    const int beg = offsets[node] + sp[node >> 10];
    const int end = (node + 1 < N) ? (offsets[node + 1] + sp[(node + 1) >> 10]) : E;

    const float4* Z4 = reinterpret_cast<const float4*>(Z);
    float4 acc = {0.f, 0.f, 0.f, 0.f};

    for (int c = beg; c < end; c += 64) {
        const int m = min(64, end - c);
        int   eid = (lane < m) ? eids[c + lane] : 0;
        int   sl  = (lane < m) ? esrc[eid] : 0;
        float wl  = (lane < m) ? ew[eid]   : 0.f;
        const int tmax = (m + 3) >> 2;
        for (int t = 0; t < tmax; ++t) {
            int  j     = slot + 4 * t;
            bool valid = j < m;
            int  js    = valid ? j : 0;
            int   s  = __shfl(sl, js, 64);
            float wv = __shfl(wl, js, 64);
            float w  = valid ? wv : 0.f;
            float4 z = Z4[(size_t)s * 16 + q];
            acc.x = fmaf(w, z.x, acc.x);
            acc.y = fmaf(w, z.y, acc.y);
            acc.z = fmaf(w, z.z, acc.z);
            acc.w = fmaf(w, z.w, acc.w);
        }
    }

#pragma unroll
    for (int off = 32; off >= 16; off >>= 1) {
        acc.x += __shfl_down(acc.x, off, 64);
        acc.y += __shfl_down(acc.y, off, 64);
        acc.z += __shfl_down(acc.z, off, 64);
        acc.w += __shfl_down(acc.w, off, 64);
    }

    if (lane < 16) {
        float4 r;
        r.x = fmaxf(acc.x, 0.f);
        r.y = fmaxf(acc.y, 0.f);
        r.z = fmaxf(acc.z, 0.f);
        r.w = fmaxf(acc.w, 0.f);
        reinterpret_cast<float4*>(out)[(size_t)node * 16 + lane] = r;
    }
}

// ---------------------------------------------------------------------------
extern "C" void kernel_launch(void* const* d_in, const int* in_sizes, int n_in,
                              void* d_out, int out_size, void* d_ws, size_t ws_size,
                              hipStream_t stream)
{
    const float* emb  = (const float*)d_in[0];  // [N, 64]
    const int*   esrc = (const int*)  d_in[1];  // [E]
    const int*   edst = (const int*)  d_in[2];  // [E]
    const float* ew   = (const float*)d_in[3];  // [E]
    const float* W    = (const float*)d_in[4];  // [64, 64]
    float*       out  = (float*)d_out;          // [N, 64]

    const int N = in_sizes[0] / D;
    const int E = in_sizes[1];

    // Workspace layout (~19.6 MB).  All segment sizes stay 16 B aligned.
    float* Z        = (float*)d_ws;               // N*64 floats (12.8 MB)
    int*   counts   = (int*)(Z + (size_t)N * D);  // N
    int*   offsets  = counts + N;                 // N
    int*   partials = offsets + N;                // 64
    int*   rank     = partials + 64;              // E
    int*   eids     = rank + E;                   // E

    hipMemsetAsync(counts, 0, (size_t)N * sizeof(int), stream);

    const int gemmTiles   = (N + 63) / 64;
    const int countBlocks = (E + 255) / 256;
    gemm_count<<<gemmTiles + countBlocks, 256, 0, stream>>>(
        emb, W, Z, edst, counts, rank, N, E, gemmTiles);

    const int nb = (N + 1023) / 1024;  // 49 <= 64
    scan_blocks<<<nb, 256, 0, stream>>>(counts, offsets, partials, N);

    fill_csr<<<((E >> 2) + 255) / 256, 256, 0, stream>>>(
        edst, rank, offsets, partials, eids, E, nb);

    gather_nodes<<<(N + 3) / 4, 256, 0, stream>>>(
        Z, offsets, partials, eids, esrc, ew, out, N, E, nb);
}

// Round 5
// 167.805 us; speedup vs baseline: 4.5778x; 1.0864x over previous
//
#include <hip/hip_runtime.h>

#define D 64  // feature dim == units == 64

// ---------------------------------------------------------------------------
// Fused kernel: blocks [0, gemmTiles) compute Z = emb @ W; remaining blocks
// count destination degrees AND record each edge's rank within its bucket
// (rank[e] = atomicAdd return, coalesced store).  Halves overlap.
// ---------------------------------------------------------------------------
__global__ __launch_bounds__(256) void gemm_count(
    const float* __restrict__ emb,
    const float* __restrict__ W,
    float*       __restrict__ Z,
    const int*   __restrict__ dst,
    int*         __restrict__ counts,
    int*         __restrict__ rank,
    int N, int E, int gemmTiles)
{
    if ((int)blockIdx.x >= gemmTiles) {
        int e = ((int)blockIdx.x - gemmTiles) * 256 + threadIdx.x;
        if (e < E) rank[e] = atomicAdd(&counts[dst[e]], 1);
        return;
    }

    const int lane = threadIdx.x & 63;
    const int wave = threadIdx.x >> 6;

    float wcol[D];
#pragma unroll
    for (int k = 0; k < D; ++k) wcol[k] = W[k * D + lane];

    __shared__ float At[64 * D];
    const int row0 = blockIdx.x * 64;

    for (int i = threadIdx.x; i < 1024; i += 256) {
        int r  = i >> 4;
        int gr = row0 + r;
        float4 v;
        if (gr < N) v = reinterpret_cast<const float4*>(emb)[(size_t)gr * 16 + (i & 15)];
        else        v = float4{0.f, 0.f, 0.f, 0.f};
        reinterpret_cast<float4*>(At)[i] = v;
    }
    __syncthreads();

    for (int rr = 0; rr < 16; ++rr) {
        int r  = wave * 16 + rr;
        int gr = row0 + r;
        if (gr >= N) break;
        const float4* arow = reinterpret_cast<const float4*>(At + r * D);
        float acc = 0.f;
#pragma unroll
        for (int k4 = 0; k4 < 16; ++k4) {
            float4 a = arow[k4];
            acc = fmaf(a.x, wcol[4 * k4 + 0], acc);
            acc = fmaf(a.y, wcol[4 * k4 + 1], acc);
            acc = fmaf(a.z, wcol[4 * k4 + 2], acc);
            acc = fmaf(a.w, wcol[4 * k4 + 3], acc);
        }
        Z[(size_t)gr * D + lane] = acc;
    }
}

// Block-level exclusive scan: each block scans 1024 elements (256 thr x 4).
// Produces per-1024-chunk-local offsets + per-chunk totals (partials).
__global__ __launch_bounds__(256) void scan_blocks(
    const int* __restrict__ counts, int* __restrict__ offsets,
    int* __restrict__ partials, int N)
{
    __shared__ int sh[256];
    const int t    = threadIdx.x;
    const int base = blockIdx.x * 1024 + t * 4;

    int v0 = (base + 0 < N) ? counts[base + 0] : 0;
    int v1 = (base + 1 < N) ? counts[base + 1] : 0;
    int v2 = (base + 2 < N) ? counts[base + 2] : 0;
    int v3 = (base + 3 < N) ? counts[base + 3] : 0;

    int s0 = v0, s1 = s0 + v1, s2 = s1 + v2, s3 = s2 + v3;
    sh[t] = s3;
    __syncthreads();
    for (int off = 1; off < 256; off <<= 1) {
        int x = (t >= off) ? sh[t - off] : 0;
        __syncthreads();
        sh[t] += x;
        __syncthreads();
    }
    int excl = sh[t] - s3;

    if (base + 0 < N) offsets[base + 0] = excl;
    if (base + 1 < N) offsets[base + 1] = excl + s0;
    if (base + 2 < N) offsets[base + 2] = excl + s1;
    if (base + 3 < N) offsets[base + 3] = excl + s2;
    if (t == 255) partials[blockIdx.x] = sh[255];
}

// Helper: first wave scans the <=64 chunk partials into LDS (exclusive).
__device__ __forceinline__ void scan_partials_lds(
    const int* __restrict__ partials, int nb, int* sp)
{
    if (threadIdx.x < 64) {
        int l    = threadIdx.x;
        int orig = (l < nb) ? partials[l] : 0;
        int v    = orig;
        for (int off = 1; off < 64; off <<= 1) {
            int x = __shfl_up(v, off, 64);
            if (l >= off) v += x;
        }
        sp[l] = v - orig;  // exclusive
    }
    __syncthreads();
}

// Fill: NO atomics.  csr[offset(dst)+rank] = {src, w_bits} — one aligned 8 B
// scattered store per edge (same 32 B sector cost as a 4 B store).
// 4 edges per thread via int4/float4 loads for ILP.
__global__ __launch_bounds__(256) void fill_csr(
    const int*   __restrict__ dst,
    const int*   __restrict__ rank,
    const int*   __restrict__ esrc,
    const float* __restrict__ ew,
    const int*   __restrict__ offsets,
    const int*   __restrict__ partials,
    int2*        __restrict__ csr,
    int E, int nb)
{
    __shared__ int sp[64];
    scan_partials_lds(partials, nb, sp);

    const int E4 = E >> 2;
    int i = blockIdx.x * 256 + threadIdx.x;
    if (i < E4) {
        int4   d4 = reinterpret_cast<const int4*>(dst)[i];
        int4   r4 = reinterpret_cast<const int4*>(rank)[i];
        int4   s4 = reinterpret_cast<const int4*>(esrc)[i];
        float4 w4 = reinterpret_cast<const float4*>(ew)[i];
        csr[offsets[d4.x] + sp[d4.x >> 10] + r4.x] = make_int2(s4.x, __float_as_int(w4.x));
        csr[offsets[d4.y] + sp[d4.y >> 10] + r4.y] = make_int2(s4.y, __float_as_int(w4.y));
        csr[offsets[d4.z] + sp[d4.z >> 10] + r4.z] = make_int2(s4.z, __float_as_int(w4.z));
        csr[offsets[d4.w] + sp[d4.w >> 10] + r4.w] = make_int2(s4.w, __float_as_int(w4.w));
    }
    // tail (E not a multiple of 4)
    if (blockIdx.x == 0 && threadIdx.x == 0) {
        for (int e = E & ~3; e < E; ++e)
            csr[offsets[dst[e]] + sp[dst[e] >> 10] + rank[e]] =
                make_int2(esrc[e], __float_as_int(ew[e]));
    }
}

// ---------------------------------------------------------------------------
// Gather: one wave per node, 4 edges in flight per wave.
// lane = (slot, q): slot = lane>>4 owns every 4th edge, q = lane&15 the float4
// within the 64-float Z row.  Each slot's 16 lanes load the SAME 8 B csr entry
// (TA broadcast, no shfl), with a 1-deep loop-carried prefetch so the next csr
// entry and the current Z row are in flight together.
// ---------------------------------------------------------------------------
__global__ __launch_bounds__(256) void gather_nodes(
    const float* __restrict__ Z,
    const int*   __restrict__ offsets,
    const int*   __restrict__ partials,
    const int2*  __restrict__ csr,
    float*       __restrict__ out,
    int N, int E, int nb)
{
    __shared__ int sp[64];
    scan_partials_lds(partials, nb, sp);

    const int node = blockIdx.x * 4 + (threadIdx.x >> 6);
    const int lane = threadIdx.x & 63;
    if (node >= N) return;

    const int slot = lane >> 4;
    const int q    = lane & 15;

    const int beg = offsets[node] + sp[node >> 10];
    const int end = (node + 1 < N) ? (offsets[node + 1] + sp[(node + 1) >> 10]) : E;

    const float4* Z4 = reinterpret_cast<const float4*>(Z);
    float4 acc = {0.f, 0.f, 0.f, 0.f};

    int  j   = beg + slot;
    int2 cur = (j < end) ? csr[j] : make_int2(0, 0);
    while (j < end) {
        const int jn  = j + 4;
        int2      nxt = (jn < end) ? csr[jn] : make_int2(0, 0);
        float     w   = __int_as_float(cur.y);
        float4    z   = Z4[(size_t)cur.x * 16 + q];
        acc.x = fmaf(w, z.x, acc.x);
        acc.y = fmaf(w, z.y, acc.y);
        acc.z = fmaf(w, z.z, acc.z);
        acc.w = fmaf(w, z.w, acc.w);
        cur = nxt;
        j   = jn;
    }

    // Reduce the 4 slots.
#pragma unroll
    for (int off = 32; off >= 16; off >>= 1) {
        acc.x += __shfl_down(acc.x, off, 64);
        acc.y += __shfl_down(acc.y, off, 64);
        acc.z += __shfl_down(acc.z, off, 64);
        acc.w += __shfl_down(acc.w, off, 64);
    }

    if (lane < 16) {
        float4 r;
        r.x = fmaxf(acc.x, 0.f);
        r.y = fmaxf(acc.y, 0.f);
        r.z = fmaxf(acc.z, 0.f);
        r.w = fmaxf(acc.w, 0.f);
        reinterpret_cast<float4*>(out)[(size_t)node * 16 + lane] = r;
    }
}

// ---------------------------------------------------------------------------
extern "C" void kernel_launch(void* const* d_in, const int* in_sizes, int n_in,
                              void* d_out, int out_size, void* d_ws, size_t ws_size,
                              hipStream_t stream)
{
    const float* emb  = (const float*)d_in[0];  // [N, 64]
    const int*   esrc = (const int*)  d_in[1];  // [E]
    const int*   edst = (const int*)  d_in[2];  // [E]
    const float* ew   = (const float*)d_in[3];  // [E]
    const float* W    = (const float*)d_in[4];  // [64, 64]
    float*       out  = (float*)d_out;          // [N, 64]

    const int N = in_sizes[0] / D;
    const int E = in_sizes[1];

    // Workspace layout (~22.7 MB).  All segments 16 B aligned.
    float* Z        = (float*)d_ws;               // N*64 floats (12.8 MB)
    int*   counts   = (int*)(Z + (size_t)N * D);  // N
    int*   offsets  = counts + N;                 // N
    int*   partials = offsets + N;                // 64
    int*   rank     = partials + 64;              // E
    int2*  csr      = (int2*)(rank + E);          // E entries {src, w_bits}

    hipMemsetAsync(counts, 0, (size_t)N * sizeof(int), stream);

    const int gemmTiles   = (N + 63) / 64;
    const int countBlocks = (E + 255) / 256;
    gemm_count<<<gemmTiles + countBlocks, 256, 0, stream>>>(
        emb, W, Z, edst, counts, rank, N, E, gemmTiles);

    const int nb = (N + 1023) / 1024;  // 49 <= 64
    scan_blocks<<<nb, 256, 0, stream>>>(counts, offsets, partials, N);

    fill_csr<<<((E >> 2) + 255) / 256, 256, 0, stream>>>(
        edst, rank, esrc, ew, offsets, partials, csr, E, nb);

    gather_nodes<<<(N + 3) / 4, 256, 0, stream>>>(
        Z, offsets, partials, csr, out, N, E, nb);
}